// Round 2
// baseline (548.072 us; speedup 1.0000x reference)
//
#include <hip/hip_runtime.h>
#include <hip/hip_bf16.h>
#include <hip/hip_fp16.h>

typedef __attribute__((ext_vector_type(8))) _Float16 half8;
typedef __attribute__((ext_vector_type(4))) float f32x4;

#define N_B 8
#define C_DIM 256
#define S_DIM 4096

__device__ __forceinline__ _Float16 f2h(float f) { return (_Float16)f; }

__device__ __forceinline__ f32x4 mfma16(half8 a, half8 b, f32x4 c) {
  return __builtin_amdgcn_mfma_f32_16x16x32_f16(a, b, c, 0, 0, 0);
}

// ---- K0: transpose x (n,C,S) fp32 -> xT (n,S,C) fp16 ----
__global__ __launch_bounds__(256) void k_transpose(const float* __restrict__ x,
                                                   _Float16* __restrict__ xT) {
  __shared__ _Float16 tile[64][65];
  int n = blockIdx.z, cb = blockIdx.y * 64, sb = blockIdx.x * 64;
  const float* xp = x + ((size_t)n * C_DIM + cb) * S_DIM + sb;
  int t = threadIdx.x;
#pragma unroll
  for (int p = 0; p < 4; ++p) {
    int row = p * 16 + (t >> 4);
    int col = (t & 15) * 4;
    float4 v4 = *(const float4*)(xp + (size_t)row * S_DIM + col);
    tile[row][col + 0] = f2h(v4.x);
    tile[row][col + 1] = f2h(v4.y);
    tile[row][col + 2] = f2h(v4.z);
    tile[row][col + 3] = f2h(v4.w);
  }
  __syncthreads();
  _Float16* op = xT + ((size_t)n * S_DIM + sb) * C_DIM + cb;
#pragma unroll
  for (int p = 0; p < 2; ++p) {
    int srow = p * 32 + (t >> 3);
    int ccol = (t & 7) * 8;
    half8 u;
#pragma unroll
    for (int i = 0; i < 8; ++i) u[i] = tile[ccol + i][srow];
    *(half8*)(op + (size_t)srow * C_DIM + ccol) = u;
  }
}

// ---- K0b: weights fp32 -> fp16 ----
__global__ __launch_bounds__(256) void k_wconv(const float* __restrict__ w0, const float* __restrict__ w1,
                                               const float* __restrict__ w2, const float* __restrict__ w3,
                                               _Float16* __restrict__ Wh) {
  int idx = blockIdx.x * 256 + threadIdx.x;
  const float* srcs[4] = {w0, w1, w2, w3};
#pragma unroll
  for (int j = 0; j < 4; ++j) {
    const float* s = srcs[j];
    for (int i = idx; i < C_DIM * C_DIM; i += 16384) Wh[j * C_DIM * C_DIM + i] = f2h(s[i]);
  }
}

// ---- K1: projection GEMMs (unchanged from round 0) ----
__global__ __launch_bounds__(256) void k_proj(const _Float16* __restrict__ xT, const _Float16* __restrict__ Wh,
                                              _Float16* __restrict__ qT, _Float16* __restrict__ kT,
                                              _Float16* __restrict__ vv, float* __restrict__ outp) {
  __shared__ __align__(16) _Float16 As[128][72];
  __shared__ __align__(16) _Float16 Bs[128][72];
  int job = blockIdx.y;
  int n = job >> 2, j = job & 3;
  const _Float16* A;
  const _Float16* B;
  int tm, tn, ldo;
  _Float16* obf = nullptr;
  float* of32 = nullptr;
  const _Float16* xTn = xT + (size_t)n * S_DIM * C_DIM;
  if (j < 2) {
    A = xTn;
    B = Wh + j * C_DIM * C_DIM;
    tm = blockIdx.x >> 1; tn = blockIdx.x & 1;
    obf = (j == 0 ? qT : kT) + (size_t)n * S_DIM * C_DIM;
    ldo = C_DIM;
  } else {
    A = Wh + j * C_DIM * C_DIM;
    B = xTn;
    tm = blockIdx.x >> 5; tn = blockIdx.x & 31;
    ldo = S_DIM;
    if (j == 2) obf = vv + (size_t)n * C_DIM * S_DIM;
    else of32 = outp + (size_t)n * C_DIM * S_DIM;
  }
  int t = threadIdx.x, w = t >> 6, lane = t & 63, r = lane & 15, q = lane >> 4;
  int wm = w >> 1, wn = w & 1;
  f32x4 acc[4][4] = {};
  for (int kc = 0; kc < 4; ++kc) {
#pragma unroll
    for (int p = 0; p < 4; ++p) {
      int row = p * 32 + (t >> 3), c8 = (t & 7) * 8;
      *(half8*)&As[row][c8] = *(const half8*)(A + (size_t)(tm * 128 + row) * C_DIM + kc * 64 + c8);
      *(half8*)&Bs[row][c8] = *(const half8*)(B + (size_t)(tn * 128 + row) * C_DIM + kc * 64 + c8);
    }
    __syncthreads();
#pragma unroll
    for (int kk = 0; kk < 2; ++kk) {
      half8 a[4], b[4];
#pragma unroll
      for (int mi = 0; mi < 4; ++mi) a[mi] = *(const half8*)&As[wm * 64 + mi * 16 + r][kk * 32 + q * 8];
#pragma unroll
      for (int ni = 0; ni < 4; ++ni) b[ni] = *(const half8*)&Bs[wn * 64 + ni * 16 + r][kk * 32 + q * 8];
#pragma unroll
      for (int mi = 0; mi < 4; ++mi)
#pragma unroll
        for (int ni = 0; ni < 4; ++ni)
          acc[mi][ni] = mfma16(a[mi], b[ni], acc[mi][ni]);
    }
    __syncthreads();
  }
#pragma unroll
  for (int mi = 0; mi < 4; ++mi)
#pragma unroll
    for (int ni = 0; ni < 4; ++ni)
#pragma unroll
      for (int jj = 0; jj < 4; ++jj) {
        int row = tm * 128 + wm * 64 + mi * 16 + q * 4 + jj;
        int col = tn * 128 + wn * 64 + ni * 16 + r;
        float val = acc[mi][ni][jj];
        if (obf) obf[(size_t)row * ldo + col] = f2h(val);
        else of32[(size_t)row * ldo + col] = val;
      }
}

// ---- K2: partial row sums  lpart[sq][n][t] = sum_{s in quarter} exp(score[t][s]) ----
// Block: 512 thr, 8 waves; owns 256 t-rows (wave w: 32 t via mt=2 subtiles), s-quarter sq.
// K fragments loop-invariant -> registers; Q staged in LDS per 64-s tile.
__global__ __launch_bounds__(512, 4) void k_rowsum(const _Float16* __restrict__ qT,
                                                   const _Float16* __restrict__ kT,
                                                   float* __restrict__ lpart) {
  __shared__ __align__(16) _Float16 Qs[64][264];
  int bid = blockIdx.x;
  int n = bid & 7, rest = bid >> 3;
  int tb = rest & 15, sq = rest >> 4;
  int t = threadIdx.x, w = t >> 6, lane = t & 63, r = lane & 15, q = lane >> 4;
  const _Float16* kp = kT + ((size_t)n * S_DIM + tb * 256 + w * 32) * C_DIM;
  const _Float16* qp = qT + ((size_t)n * S_DIM + sq * 1024) * C_DIM;
  half8 af[2][8];
#pragma unroll
  for (int mt = 0; mt < 2; ++mt)
#pragma unroll
    for (int k = 0; k < 8; ++k)
      af[mt][k] = *(const half8*)(kp + (size_t)(mt * 16 + r) * C_DIM + k * 32 + q * 8);
  float sums[2][4] = {};
  int srow = t >> 3, sc0 = (t & 7) * 8;
  for (int sc = 0; sc < 16; ++sc) {
    __syncthreads();  // protect Qs from previous iteration's readers
    {
      const _Float16* src = qp + (size_t)(sc * 64 + srow) * C_DIM + sc0;
#pragma unroll
      for (int j2 = 0; j2 < 4; ++j2)
        *(half8*)&Qs[srow][sc0 + j2 * 64] = *(const half8*)(src + j2 * 64);
    }
    __syncthreads();
    f32x4 acc[2][4] = {};
#pragma unroll
    for (int st = 0; st < 4; ++st)
#pragma unroll
      for (int k = 0; k < 8; ++k) {
        half8 b = *(const half8*)&Qs[st * 16 + r][k * 32 + q * 8];
        acc[0][st] = mfma16(af[0][k], b, acc[0][st]);
        acc[1][st] = mfma16(af[1][k], b, acc[1][st]);
      }
#pragma unroll
    for (int mt = 0; mt < 2; ++mt)
#pragma unroll
      for (int st = 0; st < 4; ++st)
#pragma unroll
        for (int jj = 0; jj < 4; ++jj)
          sums[mt][jj] += __expf(acc[mt][st][jj]);
  }
#pragma unroll
  for (int mt = 0; mt < 2; ++mt)
#pragma unroll
    for (int jj = 0; jj < 4; ++jj) {
      float v = sums[mt][jj];
      v += __shfl_xor(v, 1);
      v += __shfl_xor(v, 2);
      v += __shfl_xor(v, 4);
      v += __shfl_xor(v, 8);
      if (r == 0)
        lpart[((size_t)sq * N_B + n) * S_DIM + tb * 256 + w * 32 + mt * 16 + q * 4 + jj] = v;
    }
}

// ---- K2b: fold 1/l into V:  v'[c,t] = v[c,t] * 4096 / l_t ----
__global__ __launch_bounds__(256) void k_vscale(_Float16* __restrict__ vv, const float* __restrict__ lpart) {
  int idx = blockIdx.x * 256 + threadIdx.x;  // 1M threads, 8 halves each
  int t8 = idx & 511;
  int cn = idx >> 9;  // n*256 + c
  int n = cn >> 8;
  size_t voff = (size_t)cn * S_DIM + t8 * 8;
  half8 v = *(half8*)(vv + voff);
  const float* lp = lpart + (size_t)n * S_DIM + t8 * 8;
#pragma unroll
  for (int j = 0; j < 8; ++j) {
    float s = lp[j] + lp[N_B * S_DIM + j] + lp[2 * N_B * S_DIM + j] + lp[3 * N_B * S_DIM + j];
    v[j] = f2h((float)v[j] * (4096.0f / s));
  }
  *(half8*)(vv + voff) = v;
}

// ---- K3: attention  O += V' * exp(scores)/16, epilogue /256 ----
// Q in registers; K,V fragments direct from L2; only P goes through LDS (swizzled).
__global__ __launch_bounds__(512, 4) void k_attn(const _Float16* __restrict__ qT,
                                                 const _Float16* __restrict__ kT,
                                                 const _Float16* __restrict__ vv,
                                                 float* __restrict__ outp) {
  __shared__ __align__(16) _Float16 Ps[64 * 64];
  int bid = blockIdx.x;
  int n = bid & 7, sb = bid >> 3;
  int t = threadIdx.x, w = t >> 6, lane = t & 63, r = lane & 15, q = lane >> 4;
  int ws_ = w >> 2, wt = w & 3;
  const _Float16* qp = qT + ((size_t)n * S_DIM + sb * 64) * C_DIM;
  const _Float16* kp = kT + (size_t)n * S_DIM * C_DIM;
  const _Float16* vp = vv + (size_t)n * C_DIM * S_DIM + (size_t)(w * 32 + r) * S_DIM + q * 8;
  half8 qreg[2][8];
#pragma unroll
  for (int mi = 0; mi < 2; ++mi)
#pragma unroll
    for (int k = 0; k < 8; ++k)
      qreg[mi][k] = *(const half8*)(qp + (size_t)(ws_ * 32 + mi * 16 + r) * C_DIM + k * 32 + q * 8);
  f32x4 acc[2][4] = {};
  int wrow = ws_ * 32 + q * 4;
  int wcol = wt * 16 + r;
  for (int tc = 0; tc < 64; ++tc) {
    // QK^T: B fragments straight from kT (L2)
    f32x4 pacc[2] = {};
    const _Float16* kr = kp + (size_t)(tc * 64 + wt * 16 + r) * C_DIM + q * 8;
#pragma unroll
    for (int k = 0; k < 8; ++k) {
      half8 b = *(const half8*)(kr + k * 32);
      pacc[0] = mfma16(qreg[0][k], b, pacc[0]);
      pacc[1] = mfma16(qreg[1][k], b, pacc[1]);
    }
    __syncthreads();  // previous PV readers done with Ps
#pragma unroll
    for (int mi = 0; mi < 2; ++mi)
#pragma unroll
      for (int jj = 0; jj < 4; ++jj) {
        int row = wrow + mi * 16 + jj;
        int cs = ((wcol >> 3) ^ (row & 7));
        Ps[row * 64 + cs * 8 + (wcol & 7)] = f2h(__expf(pacc[mi][jj]) * 0.0625f);
      }
    __syncthreads();  // Ps visible
    // PV: A fragments straight from vv (L2), B from swizzled Ps
    const _Float16* vr = vp + tc * 64;
#pragma unroll
    for (int kk = 0; kk < 2; ++kk)
#pragma unroll
      for (int mi = 0; mi < 2; ++mi) {
        half8 a = *(const half8*)(vr + (size_t)mi * 16 * S_DIM + kk * 32);
#pragma unroll
        for (int ni = 0; ni < 4; ++ni) {
          int row = ni * 16 + r, col = kk * 32 + q * 8;
          int cs = ((col >> 3) ^ (row & 7));
          half8 b = *(const half8*)&Ps[row * 64 + cs * 8];
          acc[mi][ni] = mfma16(a, b, acc[mi][ni]);
        }
      }
  }
  float* ob = outp + (size_t)n * C_DIM * S_DIM + (size_t)sb * 64;
#pragma unroll
  for (int mi = 0; mi < 2; ++mi)
#pragma unroll
    for (int ni = 0; ni < 4; ++ni)
#pragma unroll
      for (int jj = 0; jj < 4; ++jj) {
        int c = w * 32 + mi * 16 + q * 4 + jj;
        int s = ni * 16 + r;
        ob[(size_t)c * S_DIM + s] += acc[mi][ni][jj] * 0.00390625f;
      }
}

extern "C" void kernel_launch(void* const* d_in, const int* in_sizes, int n_in,
                              void* d_out, int out_size, void* d_ws, size_t ws_size,
                              hipStream_t stream) {
  const float* x  = (const float*)d_in[0];
  const float* Wq = (const float*)d_in[1];
  const float* Wk = (const float*)d_in[2];
  const float* Wv = (const float*)d_in[3];
  const float* Wl = (const float*)d_in[4];
  float* out = (float*)d_out;
  char* base = (char*)d_ws;
  const size_t MB = 1024 * 1024;
  _Float16* xT = (_Float16*)(base);               // 16 MB
  _Float16* qT = (_Float16*)(base + 16 * MB);     // 16 MB
  _Float16* kT = (_Float16*)(base + 32 * MB);     // 16 MB
  _Float16* vv = (_Float16*)(base + 48 * MB);     // 16 MB
  _Float16* Wh = (_Float16*)(base + 64 * MB);     // 512 KB
  float* lpart = (float*)(base + 64 * MB + 524288);  // 4*8*4096*4 = 512 KB

  k_transpose<<<dim3(64, 4, N_B), dim3(256), 0, stream>>>(x, xT);
  k_wconv<<<dim3(64), dim3(256), 0, stream>>>(Wq, Wk, Wv, Wl, Wh);
  k_proj<<<dim3(64, 32), dim3(256), 0, stream>>>(xT, Wh, qT, kT, vv, out);
  k_rowsum<<<dim3(512), dim3(512), 0, stream>>>(qT, kT, lpart);
  k_vscale<<<dim3(4096), dim3(256), 0, stream>>>(vv, lpart);
  k_attn<<<dim3(512), dim3(512), 0, stream>>>(qT, kT, vv, out);
}

// Round 3
// 277.359 us; speedup vs baseline: 1.9760x; 1.9760x over previous
//
#include <hip/hip_runtime.h>
#include <hip/hip_bf16.h>
#include <hip/hip_fp16.h>

typedef __attribute__((ext_vector_type(8))) _Float16 half8;
typedef __attribute__((ext_vector_type(4))) float f32x4;

#define N_B 8
#define C_DIM 256
#define S_DIM 4096

__device__ __forceinline__ _Float16 f2h(float f) { return (_Float16)f; }

__device__ __forceinline__ f32x4 mfma16(half8 a, half8 b, f32x4 c) {
  return __builtin_amdgcn_mfma_f32_16x16x32_f16(a, b, c, 0, 0, 0);
}

__device__ __forceinline__ void glds16(const _Float16* src, _Float16* dst) {
  __builtin_amdgcn_global_load_lds(
      (const __attribute__((address_space(1))) void*)src,
      (__attribute__((address_space(3))) void*)dst, 16, 0, 0);
}

// ---- K0: transpose x (n,C,S) fp32 -> xT (n,S,C) fp16 ----
__global__ __launch_bounds__(256) void k_transpose(const float* __restrict__ x,
                                                   _Float16* __restrict__ xT) {
  __shared__ _Float16 tile[64][65];
  int n = blockIdx.z, cb = blockIdx.y * 64, sb = blockIdx.x * 64;
  const float* xp = x + ((size_t)n * C_DIM + cb) * S_DIM + sb;
  int t = threadIdx.x;
#pragma unroll
  for (int p = 0; p < 4; ++p) {
    int row = p * 16 + (t >> 4);
    int col = (t & 15) * 4;
    float4 v4 = *(const float4*)(xp + (size_t)row * S_DIM + col);
    tile[row][col + 0] = f2h(v4.x);
    tile[row][col + 1] = f2h(v4.y);
    tile[row][col + 2] = f2h(v4.z);
    tile[row][col + 3] = f2h(v4.w);
  }
  __syncthreads();
  _Float16* op = xT + ((size_t)n * S_DIM + sb) * C_DIM + cb;
#pragma unroll
  for (int p = 0; p < 2; ++p) {
    int srow = p * 32 + (t >> 3);
    int ccol = (t & 7) * 8;
    half8 u;
#pragma unroll
    for (int i = 0; i < 8; ++i) u[i] = tile[ccol + i][srow];
    *(half8*)(op + (size_t)srow * C_DIM + ccol) = u;
  }
}

// ---- K0b: weights fp32 -> fp16 ----
__global__ __launch_bounds__(256) void k_wconv(const float* __restrict__ w0, const float* __restrict__ w1,
                                               const float* __restrict__ w2, const float* __restrict__ w3,
                                               _Float16* __restrict__ Wh) {
  int idx = blockIdx.x * 256 + threadIdx.x;
  const float* srcs[4] = {w0, w1, w2, w3};
#pragma unroll
  for (int j = 0; j < 4; ++j) {
    const float* s = srcs[j];
    for (int i = idx; i < C_DIM * C_DIM; i += 16384) Wh[j * C_DIM * C_DIM + i] = f2h(s[i]);
  }
}

// ---- K1: projection GEMMs ----
__global__ __launch_bounds__(256) void k_proj(const _Float16* __restrict__ xT, const _Float16* __restrict__ Wh,
                                              _Float16* __restrict__ qT, _Float16* __restrict__ kT,
                                              _Float16* __restrict__ vv, float* __restrict__ outp) {
  __shared__ __align__(16) _Float16 As[128][72];
  __shared__ __align__(16) _Float16 Bs[128][72];
  int job = blockIdx.y;
  int n = job >> 2, j = job & 3;
  const _Float16* A;
  const _Float16* B;
  int tm, tn, ldo;
  _Float16* obf = nullptr;
  float* of32 = nullptr;
  const _Float16* xTn = xT + (size_t)n * S_DIM * C_DIM;
  if (j < 2) {
    A = xTn;
    B = Wh + j * C_DIM * C_DIM;
    tm = blockIdx.x >> 1; tn = blockIdx.x & 1;
    obf = (j == 0 ? qT : kT) + (size_t)n * S_DIM * C_DIM;
    ldo = C_DIM;
  } else {
    A = Wh + j * C_DIM * C_DIM;
    B = xTn;
    tm = blockIdx.x >> 5; tn = blockIdx.x & 31;
    ldo = S_DIM;
    if (j == 2) obf = vv + (size_t)n * C_DIM * S_DIM;
    else of32 = outp + (size_t)n * C_DIM * S_DIM;
  }
  int t = threadIdx.x, w = t >> 6, lane = t & 63, r = lane & 15, q = lane >> 4;
  int wm = w >> 1, wn = w & 1;
  f32x4 acc[4][4] = {};
  for (int kc = 0; kc < 4; ++kc) {
#pragma unroll
    for (int p = 0; p < 4; ++p) {
      int row = p * 32 + (t >> 3), c8 = (t & 7) * 8;
      *(half8*)&As[row][c8] = *(const half8*)(A + (size_t)(tm * 128 + row) * C_DIM + kc * 64 + c8);
      *(half8*)&Bs[row][c8] = *(const half8*)(B + (size_t)(tn * 128 + row) * C_DIM + kc * 64 + c8);
    }
    __syncthreads();
#pragma unroll
    for (int kk = 0; kk < 2; ++kk) {
      half8 a[4], b[4];
#pragma unroll
      for (int mi = 0; mi < 4; ++mi) a[mi] = *(const half8*)&As[wm * 64 + mi * 16 + r][kk * 32 + q * 8];
#pragma unroll
      for (int ni = 0; ni < 4; ++ni) b[ni] = *(const half8*)&Bs[wn * 64 + ni * 16 + r][kk * 32 + q * 8];
#pragma unroll
      for (int mi = 0; mi < 4; ++mi)
#pragma unroll
        for (int ni = 0; ni < 4; ++ni)
          acc[mi][ni] = mfma16(a[mi], b[ni], acc[mi][ni]);
    }
    __syncthreads();
  }
#pragma unroll
  for (int mi = 0; mi < 4; ++mi)
#pragma unroll
    for (int ni = 0; ni < 4; ++ni)
#pragma unroll
      for (int jj = 0; jj < 4; ++jj) {
        int row = tm * 128 + wm * 64 + mi * 16 + q * 4 + jj;
        int col = tn * 128 + wn * 64 + ni * 16 + r;
        float val = acc[mi][ni][jj];
        if (obf) obf[(size_t)row * ldo + col] = f2h(val);
        else of32[(size_t)row * ldo + col] = val;
      }
}

// ---- K2: partial row sums, K-in-regs (t=64/wave), Q dbuf via global_load_lds ----
// grid: n(8) x tb(8, 512 t each) x sq(4, 1024 s each) = 256 blocks
__global__ __launch_bounds__(512, 2) void k_rowsum(const _Float16* __restrict__ qT,
                                                   const _Float16* __restrict__ kT,
                                                   float* __restrict__ lpart) {
  __shared__ __align__(16) _Float16 Qs[2][64 * 256];
  int bid = blockIdx.x;
  int n = bid & 7, rest = bid >> 3;
  int tb = rest & 7, sq = rest >> 3;
  int t = threadIdx.x, w = t >> 6, lane = t & 63, r = lane & 15, q = lane >> 4;
  const _Float16* kp = kT + ((size_t)n * S_DIM + tb * 512 + w * 64) * C_DIM;
  const _Float16* qp = qT + ((size_t)n * S_DIM + sq * 1024) * C_DIM;
  half8 kf[4][8];
#pragma unroll
  for (int mt = 0; mt < 4; ++mt)
#pragma unroll
    for (int k = 0; k < 8; ++k)
      kf[mt][k] = *(const half8*)(kp + (size_t)(mt * 16 + r) * C_DIM + k * 32 + q * 8);
  int d0 = w * 1024 + lane * 16;
  int qswz = d0 ^ ((((w * 2) + (lane >> 5)) & 7) << 4);
  const char* qsrc0 = (const char*)qp + qswz;
#pragma unroll
  for (int i = 0; i < 4; ++i)
    glds16((const _Float16*)(qsrc0 + i * 8192), &Qs[0][i * 4096 + w * 512]);
  asm volatile("s_waitcnt vmcnt(0)" ::: "memory");
  __builtin_amdgcn_s_barrier();
  float sums[4][4] = {};
  for (int sc = 0; sc < 16; ++sc) {
    int cur = sc & 1, nxt = cur ^ 1;
    int sn = (sc + 1) & 15;
    const char* qb = qsrc0 + (size_t)sn * 32768;
#pragma unroll
    for (int i = 0; i < 4; ++i)
      glds16((const _Float16*)(qb + i * 8192), &Qs[nxt][i * 4096 + w * 512]);
#pragma unroll
    for (int st = 0; st < 4; ++st) {
      f32x4 acc[4] = {};
#pragma unroll
      for (int k = 0; k < 8; ++k) {
        int srow = st * 16 + r;
        half8 b = *(const half8*)&Qs[cur][srow * 256 + ((k * 32 + q * 8) ^ ((srow & 7) << 3))];
#pragma unroll
        for (int mt = 0; mt < 4; ++mt) acc[mt] = mfma16(kf[mt][k], b, acc[mt]);
      }
#pragma unroll
      for (int mt = 0; mt < 4; ++mt)
#pragma unroll
        for (int jj = 0; jj < 4; ++jj) sums[mt][jj] += __expf(acc[mt][jj]);
    }
    asm volatile("s_waitcnt vmcnt(0) lgkmcnt(0)" ::: "memory");
    __builtin_amdgcn_s_barrier();
  }
#pragma unroll
  for (int mt = 0; mt < 4; ++mt)
#pragma unroll
    for (int jj = 0; jj < 4; ++jj) {
      float v = sums[mt][jj];
      v += __shfl_xor(v, 1);
      v += __shfl_xor(v, 2);
      v += __shfl_xor(v, 4);
      v += __shfl_xor(v, 8);
      if (r == 0)
        lpart[((size_t)sq * N_B + n) * S_DIM + tb * 512 + w * 64 + mt * 16 + q * 4 + jj] = v;
    }
}

// ---- K2b: fold 1/l into V ----
__global__ __launch_bounds__(256) void k_vscale(_Float16* __restrict__ vv, const float* __restrict__ lpart) {
  int idx = blockIdx.x * 256 + threadIdx.x;
  int t8 = idx & 511;
  int cn = idx >> 9;
  int n = cn >> 8;
  size_t voff = (size_t)cn * S_DIM + t8 * 8;
  half8 v = *(half8*)(vv + voff);
  const float* lp = lpart + (size_t)n * S_DIM + t8 * 8;
#pragma unroll
  for (int j = 0; j < 8; ++j) {
    float s = lp[j] + lp[N_B * S_DIM + j] + lp[2 * N_B * S_DIM + j] + lp[3 * N_B * S_DIM + j];
    v[j] = f2h((float)v[j] * (4096.0f / s));
  }
  *(half8*)(vv + voff) = v;
}

// ---- K3: attention, SBLK=128, K/V dbuf via global_load_lds, counted vmcnt ----
// grid: n(8) x sb(32) = 256 blocks, 512 thr
__global__ __launch_bounds__(512, 2) void k_attn(const _Float16* __restrict__ qT,
                                                 const _Float16* __restrict__ kT,
                                                 const _Float16* __restrict__ vv,
                                                 float* __restrict__ outp) {
  __shared__ __align__(16) _Float16 Kb[2][64 * 256];   // 64KB, XOR-swz rows of 512B
  __shared__ __align__(16) _Float16 Vb[2][256 * 64];   // 64KB, XOR-swz rows of 128B
  __shared__ __align__(16) _Float16 Ps[128 * 64];      // 16KB, chunk-swz
  int bid = blockIdx.x;
  int n = bid & 7, sb = bid >> 3;
  int t = threadIdx.x, w = t >> 6, lane = t & 63, r = lane & 15, q = lane >> 4;
  int ws_ = w >> 1, wt = w & 1;   // QK: s-quarter(32), t-half(32)
  int cg = w >> 1, sg = w & 1;    // PV: c-quarter(64), s-half(64)
  const _Float16* qp = qT + ((size_t)n * S_DIM + sb * 128) * C_DIM;
  const _Float16* kpn = kT + (size_t)n * S_DIM * C_DIM;
  const _Float16* vvn = vv + (size_t)n * C_DIM * S_DIM;

  int d0 = w * 1024 + lane * 16;
  int kswz = d0 ^ ((((w * 2) + (lane >> 5)) & 7) << 4);
  const char* ksrc0 = (const char*)kpn + kswz;
  int vrow = w * 8 + (lane >> 3);
  int vcol = (((lane & 7) * 16) ^ (((lane >> 3) & 7) << 4)) >> 1;
  const _Float16* vsrc0 = vvn + (size_t)vrow * S_DIM + vcol;

  half8 qreg[2][8];
#pragma unroll
  for (int mi = 0; mi < 2; ++mi)
#pragma unroll
    for (int k = 0; k < 8; ++k)
      qreg[mi][k] = *(const half8*)(qp + (size_t)(ws_ * 32 + mi * 16 + r) * C_DIM + k * 32 + q * 8);

  // prologue: stage tile 0 into buf 0 (K then V)
#pragma unroll
  for (int i = 0; i < 4; ++i)
    glds16((const _Float16*)(ksrc0 + i * 8192), &Kb[0][i * 4096 + w * 512]);
#pragma unroll
  for (int i = 0; i < 4; ++i)
    glds16(vsrc0 + (size_t)i * 64 * S_DIM, &Vb[0][i * 4096 + w * 512]);
  asm volatile("s_waitcnt vmcnt(4)" ::: "memory");
  __builtin_amdgcn_s_barrier();

  f32x4 acc[4][4] = {};
  for (int tc = 0; tc < 64; ++tc) {
    int cur = tc & 1, nxt = cur ^ 1;
    int tn = (tc + 1) & 63;
    // stage K[next] (safe: K[nxt] last read in QK(tc-1), done before barrier B(tc-1))
    const char* kb = ksrc0 + (size_t)tn * 32768;
#pragma unroll
    for (int i = 0; i < 4; ++i)
      glds16((const _Float16*)(kb + i * 8192), &Kb[nxt][i * 4096 + w * 512]);
    // QK^T -> pacc (scores^T: s rows, t cols)
    f32x4 pacc[2][2] = {};
#pragma unroll
    for (int k = 0; k < 8; ++k)
#pragma unroll
      for (int ti = 0; ti < 2; ++ti) {
        int trow = wt * 32 + ti * 16 + r;
        half8 b = *(const half8*)&Kb[cur][trow * 256 + ((k * 32 + q * 8) ^ ((trow & 7) << 3))];
        pacc[0][ti] = mfma16(qreg[0][k], b, pacc[0][ti]);
        pacc[1][ti] = mfma16(qreg[1][k], b, pacc[1][ti]);
      }
    asm volatile("s_waitcnt lgkmcnt(0)" ::: "memory");
    __builtin_amdgcn_s_barrier();   // A: all PV(tc-1) readers done -> Ps, Vb[nxt] free
    // stage V[next]
    const _Float16* vb = vsrc0 + tn * 64;
#pragma unroll
    for (int i = 0; i < 4; ++i)
      glds16(vb + (size_t)i * 64 * S_DIM, &Vb[nxt][i * 4096 + w * 512]);
    // exp + write P (P = exp/16)
#pragma unroll
    for (int mi = 0; mi < 2; ++mi)
#pragma unroll
      for (int ti = 0; ti < 2; ++ti)
#pragma unroll
        for (int jj = 0; jj < 4; ++jj) {
          int srow = ws_ * 32 + mi * 16 + q * 4 + jj;
          int tcol = wt * 32 + ti * 16 + r;
          Ps[srow * 64 + ((((tcol >> 3) ^ (srow & 7)) << 3) | (tcol & 7))] =
              f2h(__expf(pacc[mi][ti][jj]) * 0.0625f);
        }
    // counted wait: completes K[nxt] + V[cur] (from prev iter); leaves this V[nxt] in flight
    asm volatile("s_waitcnt vmcnt(4) lgkmcnt(0)" ::: "memory");
    __builtin_amdgcn_s_barrier();   // B: Ps visible; K[nxt], V[cur] staged
    // PV: O += V' * P
#pragma unroll
    for (int kk = 0; kk < 2; ++kk) {
      half8 a[4];
#pragma unroll
      for (int mi = 0; mi < 4; ++mi) {
        int crow = cg * 64 + mi * 16 + r;
        a[mi] = *(const half8*)&Vb[cur][crow * 64 + ((kk * 32 + q * 8) ^ ((crow & 7) << 3))];
      }
#pragma unroll
      for (int ni = 0; ni < 4; ++ni) {
        int srow = sg * 64 + ni * 16 + r;
        half8 pb = *(const half8*)&Ps[srow * 64 + (((kk * 4 + q) ^ (srow & 7)) << 3)];
#pragma unroll
        for (int mi = 0; mi < 4; ++mi)
          acc[mi][ni] = mfma16(a[mi], pb, acc[mi][ni]);
      }
    }
  }
  float* ob = outp + (size_t)n * C_DIM * S_DIM + (size_t)sb * 128;
#pragma unroll
  for (int mi = 0; mi < 4; ++mi)
#pragma unroll
    for (int ni = 0; ni < 4; ++ni)
#pragma unroll
      for (int jj = 0; jj < 4; ++jj) {
        int c = cg * 64 + mi * 16 + q * 4 + jj;
        int s = sg * 64 + ni * 16 + r;
        ob[(size_t)c * S_DIM + s] += acc[mi][ni][jj] * 0.00390625f;
      }
}

extern "C" void kernel_launch(void* const* d_in, const int* in_sizes, int n_in,
                              void* d_out, int out_size, void* d_ws, size_t ws_size,
                              hipStream_t stream) {
  const float* x  = (const float*)d_in[0];
  const float* Wq = (const float*)d_in[1];
  const float* Wk = (const float*)d_in[2];
  const float* Wv = (const float*)d_in[3];
  const float* Wl = (const float*)d_in[4];
  float* out = (float*)d_out;
  char* base = (char*)d_ws;
  const size_t MB = 1024 * 1024;
  _Float16* xT = (_Float16*)(base);
  _Float16* qT = (_Float16*)(base + 16 * MB);
  _Float16* kT = (_Float16*)(base + 32 * MB);
  _Float16* vv = (_Float16*)(base + 48 * MB);
  _Float16* Wh = (_Float16*)(base + 64 * MB);
  float* lpart = (float*)(base + 64 * MB + 524288);

  k_transpose<<<dim3(64, 4, N_B), dim3(256), 0, stream>>>(x, xT);
  k_wconv<<<dim3(64), dim3(256), 0, stream>>>(Wq, Wk, Wv, Wl, Wh);
  k_proj<<<dim3(64, 32), dim3(256), 0, stream>>>(xT, Wh, qT, kT, vv, out);
  k_rowsum<<<dim3(256), dim3(512), 0, stream>>>(qT, kT, lpart);
  k_vscale<<<dim3(4096), dim3(256), 0, stream>>>(vv, lpart);
  k_attn<<<dim3(256), dim3(512), 0, stream>>>(qT, kT, vv, out);
}